// Round 2
// baseline (907.954 us; speedup 1.0000x reference)
//
#include <hip/hip_runtime.h>

// RelationAwareAttention: B=2,H=8,L=2048,DK=64  (fp32 I/O, bf16 comparison space)
//   s = (Q K^T + tree + leaf) / sqrt(192); s[mask]= -1e9; p=softmax(s); O=pV
// Outputs concatenated: [attn_sum (B,H,L,DK) ; p_attn (B,H,L,L)], fp32.
// One WG per (bh, 16-row tile). Phase 1: QK^T via MFMA (Q/K cast to bf16
// in-kernel), add coalesced fp32 tree/leaf streams + int32 mask, write fp32
// scores into the p_attn region (scratch-in-place, L2/L3-hot), keep online
// per-row (m,l). Phase 2: read scores back, overwrite with p, PV via MFMA.

#define B_   2
#define H_   8
#define L_   2048
#define DK_  64
#define BH_  16
#define M_   16                      // query rows per workgroup
#define SCALE 0.07216878364870323f   // 1/sqrt(3*64)

typedef __attribute__((ext_vector_type(8))) short  short8;   // 8 x bf16 bits
typedef __attribute__((ext_vector_type(4))) float  f32x4;

__device__ __forceinline__ unsigned short f2bf(float f) {
    union { float f; unsigned int i; } x; x.f = f;
    unsigned int u = x.i;
    return (unsigned short)((u + 0x7fffu + ((u >> 16) & 1u)) >> 16);  // RNE
}
__device__ __forceinline__ short8 pack8(float4 a, float4 b) {
    short8 r;
    r[0] = (short)f2bf(a.x); r[1] = (short)f2bf(a.y);
    r[2] = (short)f2bf(a.z); r[3] = (short)f2bf(a.w);
    r[4] = (short)f2bf(b.x); r[5] = (short)f2bf(b.y);
    r[6] = (short)f2bf(b.z); r[7] = (short)f2bf(b.w);
    return r;
}

__global__ __launch_bounds__(256)
void raa_fused_kernel(const float* __restrict__ q,
                      const float* __restrict__ k,
                      const float* __restrict__ v,
                      const int*   __restrict__ mask,   // (B,1,L,L)
                      const float* __restrict__ tree,
                      const float* __restrict__ leaf,
                      float*       __restrict__ attn,   // (B,H,L,DK)
                      float*       __restrict__ p)      // (B,H,L,L)
{
    const int t    = threadIdx.x;
    const int wv   = t >> 6;        // wave 0..3
    const int lane = t & 63;
    const int bh   = blockIdx.x;    // 0..15
    const int b    = bh >> 3;
    const int i0   = blockIdx.y * M_;

    __shared__ float          s_qk[16][68];    // fp32 QK^T tile (pad: 2-way banks, free)
    __shared__ unsigned short s_p[16][136];    // bf16 p chunk for PV A-frags
    __shared__ float          s_m[16], s_linv[16];

    // A-operand (Q) fragments: row m=lane&15, k=(lane>>4)*8.. (bf16-packed)
    const size_t qbase = ((size_t)bh * L_ + i0 + (lane & 15)) * DK_ + ((lane >> 4) * 8);
    const short8 aq0 = pack8(*(const float4*)(q + qbase),      *(const float4*)(q + qbase + 4));
    const short8 aq1 = pack8(*(const float4*)(q + qbase + 32), *(const float4*)(q + qbase + 36));

    const size_t bias_row0 = (size_t)bh * L_ * L_ + (size_t)i0 * L_;  // tree/leaf/p
    const size_t mask_row0 = (size_t)b  * L_ * L_ + (size_t)i0 * L_;

    const int prow = t >> 4;          // stream phase: thread owns (row prow, cols ...)
    const int pc4  = (t & 15) * 4;

    float m_run = -INFINITY;
    float l_run = 0.f;

    // ---------------- Phase 1: scores + online (m,l) ----------------
    for (int jc = 0; jc < L_ / 64; ++jc) {
        const int j0 = jc * 64;
        {   // wave wv: 16x16 S-tile at columns j0 + wv*16 (2 MFMAs over DK=64)
            const size_t kbase = ((size_t)bh * L_ + j0 + wv * 16 + (lane & 15)) * DK_
                               + ((lane >> 4) * 8);
            const short8 kb0 = pack8(*(const float4*)(k + kbase),
                                     *(const float4*)(k + kbase + 4));
            const short8 kb1 = pack8(*(const float4*)(k + kbase + 32),
                                     *(const float4*)(k + kbase + 36));
            f32x4 acc = {0.f, 0.f, 0.f, 0.f};
            acc = __builtin_amdgcn_mfma_f32_16x16x32_bf16(aq0, kb0, acc, 0, 0, 0);
            acc = __builtin_amdgcn_mfma_f32_16x16x32_bf16(aq1, kb1, acc, 0, 0, 0);
            const int r0 = (lane >> 4) * 4;           // C-layout: row=(lane>>4)*4+r
            const int cc = wv * 16 + (lane & 15);     //           col=lane&15
            s_qk[r0 + 0][cc] = acc[0];
            s_qk[r0 + 1][cc] = acc[1];
            s_qk[r0 + 2][cc] = acc[2];
            s_qk[r0 + 3][cc] = acc[3];
        }
        __syncthreads();
        {   // coalesced bias/mask streams; thread t -> (row prow, 4 cols)
            const float4 qk4 = *(const float4*)&s_qk[prow][pc4];
            const size_t off = bias_row0 + (size_t)prow * L_ + j0 + pc4;
            const float4 t4 = *(const float4*)(tree + off);
            const float4 l4 = *(const float4*)(leaf + off);
            const int4   mk = *(const int4*)(mask + mask_row0 + (size_t)prow * L_ + j0 + pc4);
            const float s0 = mk.x ? -1e9f : (qk4.x + t4.x + l4.x) * SCALE;
            const float s1 = mk.y ? -1e9f : (qk4.y + t4.y + l4.y) * SCALE;
            const float s2 = mk.z ? -1e9f : (qk4.z + t4.z + l4.z) * SCALE;
            const float s3 = mk.w ? -1e9f : (qk4.w + t4.w + l4.w) * SCALE;
            float4 sv; sv.x = s0; sv.y = s1; sv.z = s2; sv.w = s3;
            *(float4*)(p + off) = sv;                  // score scratch into p_attn region
            float rmax = fmaxf(fmaxf(s0, s1), fmaxf(s2, s3));
            for (int d = 8; d >= 1; d >>= 1) rmax = fmaxf(rmax, __shfl_xor(rmax, d));
            const float m_new = fmaxf(m_run, rmax);
            float e = __expf(s0 - m_new) + __expf(s1 - m_new)
                    + __expf(s2 - m_new) + __expf(s3 - m_new);
            for (int d = 8; d >= 1; d >>= 1) e += __shfl_xor(e, d);
            l_run = l_run * __expf(m_run - m_new) + e;
            m_run = m_new;
        }
        __syncthreads();
    }

    if ((t & 15) == 0) { s_m[prow] = m_run; s_linv[prow] = 1.f / l_run; }
    __syncthreads();

    // ---------------- Phase 2: p = exp(s-m)/l  and  O = p V ----------------
    f32x4 oacc = {0.f, 0.f, 0.f, 0.f};
    const int c8 = (t & 15) * 8;
    for (int pcnk = 0; pcnk < L_ / 128; ++pcnk) {
        const int j0 = pcnk * 128;
        {   // normalize a 16x128 chunk in place, stash bf16 p in LDS
            const size_t off = bias_row0 + (size_t)prow * L_ + j0 + c8;
            const float4 sv0 = *(const float4*)(p + off);
            const float4 sv1 = *(const float4*)(p + off + 4);
            const float mrow = s_m[prow], li = s_linv[prow];
            float4 p0, p1;
            p0.x = __expf(sv0.x - mrow) * li;  p0.y = __expf(sv0.y - mrow) * li;
            p0.z = __expf(sv0.z - mrow) * li;  p0.w = __expf(sv0.w - mrow) * li;
            p1.x = __expf(sv1.x - mrow) * li;  p1.y = __expf(sv1.y - mrow) * li;
            p1.z = __expf(sv1.z - mrow) * li;  p1.w = __expf(sv1.w - mrow) * li;
            *(float4*)(p + off)     = p0;
            *(float4*)(p + off + 4) = p1;
            *(short8*)&s_p[prow][c8] = pack8(p0, p1);
        }
        __syncthreads();
        {   // wave wv accumulates O columns wv*16..wv*16+15
#pragma unroll
            for (int kk = 0; kk < 4; ++kk) {
                const short8 af = *(const short8*)&s_p[lane & 15][kk * 32 + (lane >> 4) * 8];
                const float* vp = v + ((size_t)bh * L_ + j0 + kk * 32 + (lane >> 4) * 8) * DK_
                                    + wv * 16 + (lane & 15);
                short8 bfr;
#pragma unroll
                for (int u = 0; u < 8; ++u) bfr[u] = (short)f2bf(vp[(size_t)u * DK_]);
                oacc = __builtin_amdgcn_mfma_f32_16x16x32_bf16(af, bfr, oacc, 0, 0, 0);
            }
        }
        __syncthreads();
    }

    {   // epilogue: C-layout -> attn_sum (fp32)
        const int r0  = (lane >> 4) * 4;
        const int col = wv * 16 + (lane & 15);
#pragma unroll
        for (int r = 0; r < 4; ++r)
            attn[((size_t)bh * L_ + i0 + r0 + r) * DK_ + col] = oacc[r];
    }
}

extern "C" void kernel_launch(void* const* d_in, const int* in_sizes, int n_in,
                              void* d_out, int out_size, void* d_ws, size_t ws_size,
                              hipStream_t stream) {
    const float* q    = (const float*)d_in[0];
    const float* k    = (const float*)d_in[1];
    const float* v    = (const float*)d_in[2];
    const int*   mask = (const int*)d_in[3];
    const float* tree = (const float*)d_in[4];
    const float* leaf = (const float*)d_in[5];

    float* attn = (float*)d_out;
    float* p    = attn + (size_t)B_ * H_ * L_ * DK_;  // + 2,097,152 floats

    dim3 grid(BH_, L_ / M_);   // (16, 128)
    raa_fused_kernel<<<grid, 256, 0, stream>>>(q, k, v, mask, tree, leaf, attn, p);
}